// Round 1
// baseline (676.704 us; speedup 1.0000x reference)
//
#include <hip/hip_runtime.h>
#include <hip/hip_bf16.h>

#define N_NODES 100000
#define N_EDGES 3200000
#define D 128

// ---------------- degree count ----------------
__global__ __launch_bounds__(256) void count_deg(const int* __restrict__ ei,
                                                 int* __restrict__ degcnt) {
    int e = blockIdx.x * 256 + threadIdx.x;
    if (e < N_EDGES) atomicAdd(&degcnt[ei[e]], 1);
}

// ---------------- dinv = rsqrt(deg) ----------------
__global__ __launch_bounds__(256) void dinv_k(const int* __restrict__ degcnt,
                                              float* __restrict__ dinv) {
    int i = blockIdx.x * 256 + threadIdx.x;
    if (i < N_NODES) {
        int d = degcnt[i];
        dinv[i] = (d > 0) ? rsqrtf((float)d) : 0.0f;
    }
}

// ---------------- scan (3-phase exclusive prefix sum over degcnt) ----------------
__global__ __launch_bounds__(1024) void scan1(const int* __restrict__ degcnt,
                                              int* __restrict__ rowptr,
                                              int* __restrict__ bsums) {
    __shared__ int s[1024];
    int tid = threadIdx.x;
    int gi = blockIdx.x * 1024 + tid;
    int v = (gi < N_NODES) ? degcnt[gi] : 0;
    s[tid] = v;
    __syncthreads();
    for (int off = 1; off < 1024; off <<= 1) {
        int t = (tid >= off) ? s[tid - off] : 0;
        __syncthreads();
        s[tid] += t;
        __syncthreads();
    }
    if (gi < N_NODES) rowptr[gi] = s[tid] - v;   // per-block exclusive
    if (tid == 1023) bsums[blockIdx.x] = s[1023];
}

__global__ __launch_bounds__(128) void scan2(int* __restrict__ bsums, int nb) {
    __shared__ int s[128];
    int tid = threadIdx.x;
    int v = (tid < nb) ? bsums[tid] : 0;
    s[tid] = v;
    __syncthreads();
    for (int off = 1; off < 128; off <<= 1) {
        int t = (tid >= off) ? s[tid - off] : 0;
        __syncthreads();
        s[tid] += t;
        __syncthreads();
    }
    if (tid < nb) bsums[tid] = s[tid] - v;       // exclusive block offsets
}

__global__ __launch_bounds__(256) void scan3(int* __restrict__ rowptr,
                                             const int* __restrict__ bsums,
                                             int* __restrict__ cursor) {
    int gi = blockIdx.x * 256 + threadIdx.x;
    if (gi < N_NODES) {
        int v = rowptr[gi] + bsums[gi >> 10];
        rowptr[gi] = v;
        cursor[gi] = v;
    }
    if (gi == 0) rowptr[N_NODES] = N_EDGES;
}

// ---------------- scatter edges into CSR ----------------
__global__ __launch_bounds__(256) void scatter_k(const int* __restrict__ ei,
                                                 const float* __restrict__ dinv,
                                                 int* __restrict__ cursor,
                                                 int2* __restrict__ edges) {
    int e = blockIdx.x * 256 + threadIdx.x;
    if (e < N_EDGES) {
        int r = ei[e];
        int c = ei[N_EDGES + e];
        float w = dinv[r] * dinv[c];
        int pos = atomicAdd(&cursor[r], 1);
        edges[pos] = make_int2(c, __float_as_int(w));
    }
}

// ---------------- xl = x @ W.T + b  (f32, LDS-tiled) ----------------
// BM=64 nodes, BN=128 (all outputs), BK=32. 256 threads; each thread 4x8 outputs.
__global__ __launch_bounds__(256) void gemm_k(const float* __restrict__ x,
                                              const float* __restrict__ W,
                                              const float* __restrict__ b,
                                              float* __restrict__ xl) {
    __shared__ float As[32][68];    // [k][m], padded
    __shared__ float Bs[32][132];   // [k][n], padded
    int tid = threadIdx.x;
    int bm = blockIdx.x * 64;
    int tm = tid >> 4;      // 0..15
    int tn = tid & 15;      // 0..15
    int m0 = tm * 4;
    int n0 = tn * 4;        // second half at n0+64

    float c[4][8];
#pragma unroll
    for (int i = 0; i < 4; ++i)
#pragma unroll
        for (int j = 0; j < 8; ++j) c[i][j] = 0.0f;

    for (int kt = 0; kt < D; kt += 32) {
        // stage A (x tile, transposed into [k][m])
#pragma unroll
        for (int it = 0; it < 2; ++it) {
            int lin = it * 256 + tid;       // 0..511
            int m = lin & 63;
            int kq = lin >> 6;              // 0..7
            int gm = bm + m;
            if (gm >= N_NODES) gm = N_NODES - 1;
            float4 v = *(const float4*)&x[(size_t)gm * D + kt + kq * 4];
            As[kq * 4 + 0][m] = v.x;
            As[kq * 4 + 1][m] = v.y;
            As[kq * 4 + 2][m] = v.z;
            As[kq * 4 + 3][m] = v.w;
        }
        // stage B (W rows, transposed into [k][n]); Bs[k][n] = W[n][kt+k]
#pragma unroll
        for (int it = 0; it < 4; ++it) {
            int lin = it * 1024 + tid * 4;  // multiples of 4
            int n = lin >> 5;               // 0..127
            int k4 = lin & 31;              // 0,4,...,28
            float4 v = *(const float4*)&W[n * D + kt + k4];
            Bs[k4 + 0][n] = v.x;
            Bs[k4 + 1][n] = v.y;
            Bs[k4 + 2][n] = v.z;
            Bs[k4 + 3][n] = v.w;
        }
        __syncthreads();
#pragma unroll
        for (int k = 0; k < 32; ++k) {
            float4 a  = *(const float4*)&As[k][m0];
            float4 b0 = *(const float4*)&Bs[k][n0];
            float4 b1 = *(const float4*)&Bs[k][n0 + 64];
            float av[4] = {a.x, a.y, a.z, a.w};
            float bv[8] = {b0.x, b0.y, b0.z, b0.w, b1.x, b1.y, b1.z, b1.w};
#pragma unroll
            for (int i = 0; i < 4; ++i)
#pragma unroll
                for (int j = 0; j < 8; ++j) c[i][j] += av[i] * bv[j];
        }
        __syncthreads();
    }

    float4 bv0 = *(const float4*)&b[n0];
    float4 bv1 = *(const float4*)&b[n0 + 64];
#pragma unroll
    for (int i = 0; i < 4; ++i) {
        int gm = bm + m0 + i;
        if (gm < N_NODES) {
            float4 o0 = make_float4(c[i][0] + bv0.x, c[i][1] + bv0.y,
                                    c[i][2] + bv0.z, c[i][3] + bv0.w);
            float4 o1 = make_float4(c[i][4] + bv1.x, c[i][5] + bv1.y,
                                    c[i][6] + bv1.z, c[i][7] + bv1.w);
            *(float4*)&xl[(size_t)gm * D + n0] = o0;
            *(float4*)&xl[(size_t)gm * D + n0 + 64] = o1;
        }
    }
}

// ---------------- aggregation: one wave per node, float2 per lane ----------------
__global__ __launch_bounds__(256) void aggregate(const int2* __restrict__ edges,
                                                 const int* __restrict__ rowptr,
                                                 const float* __restrict__ xl,
                                                 float* __restrict__ out) {
    int gw = (blockIdx.x * 256 + threadIdx.x) >> 6;
    int lane = threadIdx.x & 63;
    if (gw >= N_NODES) return;
    int s = rowptr[gw];
    int e = rowptr[gw + 1];
    const float2* xl2 = (const float2*)xl;
    float ax = 0.0f, ay = 0.0f;
    int i = s;
    for (; i + 2 <= e; i += 2) {
        int2 e0 = edges[i];
        int2 e1 = edges[i + 1];
        float2 v0 = xl2[e0.x * 64 + lane];
        float2 v1 = xl2[e1.x * 64 + lane];
        float w0 = __int_as_float(e0.y);
        float w1 = __int_as_float(e1.y);
        ax += w0 * v0.x;
        ay += w0 * v0.y;
        ax += w1 * v1.x;
        ay += w1 * v1.y;
    }
    if (i < e) {
        int2 e0 = edges[i];
        float2 v0 = xl2[e0.x * 64 + lane];
        float w0 = __int_as_float(e0.y);
        ax += w0 * v0.x;
        ay += w0 * v0.y;
    }
    float2 r;
    r.x = ax;
    r.y = ay;
    ((float2*)out)[(size_t)gw * 64 + lane] = r;
}

extern "C" void kernel_launch(void* const* d_in, const int* in_sizes, int n_in,
                              void* d_out, int out_size, void* d_ws, size_t ws_size,
                              hipStream_t stream) {
    const float* x  = (const float*)d_in[0];
    const int*   ei = (const int*)d_in[1];
    const float* W  = (const float*)d_in[2];
    const float* b  = (const float*)d_in[3];
    float* out = (float*)d_out;

    // workspace layout (all 4-byte units)
    float* ws = (float*)d_ws;
    float* xl     = ws;                              // 12,800,000 f32
    int*   degcnt = (int*)(ws + 12800000);           // 100,096
    float* dinv   = (float*)(ws + 12900096);         // 100,096
    int*   rowptr = (int*)(ws + 13000192);           // 100,160 (needs 100,001)
    int*   cursor = (int*)(ws + 13100352);           // 100,096
    int*   bsums  = (int*)(ws + 13200448);           // 128
    int2*  edges  = (int2*)(ws + 13200576);          // 3.2M int2 = 6.4M ints
    // total ≈ 19.6M * 4B ≈ 78.4 MB

    hipMemsetAsync(degcnt, 0, N_NODES * sizeof(int), stream);

    count_deg<<<(N_EDGES + 255) / 256, 256, 0, stream>>>(ei, degcnt);

    const int nb = (N_NODES + 1023) / 1024;          // 98
    scan1<<<nb, 1024, 0, stream>>>(degcnt, rowptr, bsums);
    dinv_k<<<(N_NODES + 255) / 256, 256, 0, stream>>>(degcnt, dinv);
    scan2<<<1, 128, 0, stream>>>(bsums, nb);
    scan3<<<(N_NODES + 255) / 256, 256, 0, stream>>>(rowptr, bsums, cursor);

    scatter_k<<<(N_EDGES + 255) / 256, 256, 0, stream>>>(ei, dinv, cursor, edges);

    gemm_k<<<(N_NODES + 63) / 64, 256, 0, stream>>>(x, W, b, xl);

    aggregate<<<(N_NODES * 64 + 255) / 256, 256, 0, stream>>>(edges, rowptr, xl, out);
}

// Round 3
// 674.315 us; speedup vs baseline: 1.0035x; 1.0035x over previous
//
#include <hip/hip_runtime.h>
#include <hip/hip_bf16.h>

#define N_NODES 100000
#define N_EDGES 3200000
#define D 128

typedef __attribute__((ext_vector_type(8))) short short8v;   // 8 bf16 (4 VGPRs)
typedef __attribute__((ext_vector_type(4))) float f32x4;

static __device__ __forceinline__ short f2bf(float f) {
    __hip_bfloat16 h = __float2bfloat16(f);
    return __builtin_bit_cast(short, h);
}

// ---------------- degree count ----------------
__global__ __launch_bounds__(256) void count_deg(const int* __restrict__ ei,
                                                 int* __restrict__ degcnt) {
    int e = blockIdx.x * 256 + threadIdx.x;
    if (e < N_EDGES) atomicAdd(&degcnt[ei[e]], 1);
}

// ---------------- dinv = rsqrt(deg) ----------------
__global__ __launch_bounds__(256) void dinv_k(const int* __restrict__ degcnt,
                                              float* __restrict__ dinv) {
    int i = blockIdx.x * 256 + threadIdx.x;
    if (i < N_NODES) {
        int d = degcnt[i];
        dinv[i] = (d > 0) ? rsqrtf((float)d) : 0.0f;
    }
}

// ---------------- scan (3-phase exclusive prefix sum over degcnt) ----------------
__global__ __launch_bounds__(1024) void scan1(const int* __restrict__ degcnt,
                                              int* __restrict__ rowptr,
                                              int* __restrict__ bsums) {
    __shared__ int s[1024];
    int tid = threadIdx.x;
    int gi = blockIdx.x * 1024 + tid;
    int v = (gi < N_NODES) ? degcnt[gi] : 0;
    s[tid] = v;
    __syncthreads();
    for (int off = 1; off < 1024; off <<= 1) {
        int t = (tid >= off) ? s[tid - off] : 0;
        __syncthreads();
        s[tid] += t;
        __syncthreads();
    }
    if (gi < N_NODES) rowptr[gi] = s[tid] - v;   // per-block exclusive
    if (tid == 1023) bsums[blockIdx.x] = s[1023];
}

__global__ __launch_bounds__(128) void scan2(int* __restrict__ bsums, int nb) {
    __shared__ int s[128];
    int tid = threadIdx.x;
    int v = (tid < nb) ? bsums[tid] : 0;
    s[tid] = v;
    __syncthreads();
    for (int off = 1; off < 128; off <<= 1) {
        int t = (tid >= off) ? s[tid - off] : 0;
        __syncthreads();
        s[tid] += t;
        __syncthreads();
    }
    if (tid < nb) bsums[tid] = s[tid] - v;       // exclusive block offsets
}

__global__ __launch_bounds__(256) void scan3(int* __restrict__ rowptr,
                                             const int* __restrict__ bsums,
                                             int* __restrict__ cursor) {
    int gi = blockIdx.x * 256 + threadIdx.x;
    if (gi < N_NODES) {
        int v = rowptr[gi] + bsums[gi >> 10];
        rowptr[gi] = v;
        cursor[gi] = v;
    }
    if (gi == 0) rowptr[N_NODES] = N_EDGES;
}

// ---------------- scatter edges into CSR (col index only) ----------------
__global__ __launch_bounds__(256) void scatter_k(const int* __restrict__ ei,
                                                 int* __restrict__ cursor,
                                                 int* __restrict__ edges) {
    int e = blockIdx.x * 256 + threadIdx.x;
    if (e < N_EDGES) {
        int r = ei[e];
        int c = ei[N_EDGES + e];
        int pos = atomicAdd(&cursor[r], 1);
        edges[pos] = c;
    }
}

// ---------------- W f32 -> bf16 ----------------
__global__ __launch_bounds__(256) void convW(const float* __restrict__ W,
                                             __hip_bfloat16* __restrict__ Wb) {
    int i = blockIdx.x * 256 + threadIdx.x;
    if (i < D * D) Wb[i] = __float2bfloat16(W[i]);
}

// ---------------- xl = bf16(x @ W.T + b), MFMA 16x16x32 ----------------
// Block = 256 thr = 4 waves; each wave: 16 M-rows x 128 N. No LDS staging for
// operands (fragment layouts map to contiguous per-lane row loads); LDS only
// for the epilogue transpose so xl stores are coalesced 16B/lane.
__global__ __launch_bounds__(256) void gemm_mfma(const float* __restrict__ x,
                                                 const __hip_bfloat16* __restrict__ Wb,
                                                 const float* __restrict__ b,
                                                 __hip_bfloat16* __restrict__ xl) {
    __shared__ __hip_bfloat16 lds[4][16][136];   // per-wave transpose buffer
    int tid = threadIdx.x;
    int w = tid >> 6;
    int l = tid & 63;
    int lm = l & 15;         // A-row / B-col within frag
    int kb = l >> 4;         // k-block 0..3 (k = kb*8 + j)
    int bm = blockIdx.x * 64 + w * 16;

    int row = bm + lm;
    if (row >= N_NODES) row = N_NODES - 1;       // dup compute; stores guarded
    const float* xr = x + (size_t)row * D;

    // A fragments: x[row][ks*32 + kb*8 .. +8], cvt f32->bf16
    short8v a[4];
#pragma unroll
    for (int ks = 0; ks < 4; ++ks) {
        const float* p = xr + ks * 32 + kb * 8;
        float4 u = *(const float4*)p;
        float4 v = *(const float4*)(p + 4);
        short8v t;
        t[0] = f2bf(u.x); t[1] = f2bf(u.y); t[2] = f2bf(u.z); t[3] = f2bf(u.w);
        t[4] = f2bf(v.x); t[5] = f2bf(v.y); t[6] = f2bf(v.z); t[7] = f2bf(v.w);
        a[ks] = t;
    }

    f32x4 acc[8];
#pragma unroll
    for (int nf = 0; nf < 8; ++nf) {
        acc[nf][0] = 0.f; acc[nf][1] = 0.f; acc[nf][2] = 0.f; acc[nf][3] = 0.f;
    }

    const short8v* Wv = reinterpret_cast<const short8v*>(Wb);
#pragma unroll
    for (int ks = 0; ks < 4; ++ks) {
#pragma unroll
        for (int nf = 0; nf < 8; ++nf) {
            // B frag: Wb[nf*16+lm][ks*32 + kb*8 .. +8]  (B[k][n] = W[n][k])
            short8v bf = Wv[(nf * 16 + lm) * 16 + ks * 4 + kb];
            acc[nf] = __builtin_amdgcn_mfma_f32_16x16x32_bf16(a[ks], bf, acc[nf], 0, 0, 0);
        }
    }

    // epilogue: bias, cvt, transpose via LDS, coalesced bf16x8 stores
#pragma unroll
    for (int nf = 0; nf < 8; ++nf) {
        float bias = b[nf * 16 + lm];
#pragma unroll
        for (int j = 0; j < 4; ++j) {
            // D: col = lane&15 (n), row = (lane>>4)*4 + j
            lds[w][kb * 4 + j][nf * 16 + lm] = __float2bfloat16(acc[nf][j] + bias);
        }
    }
    __syncthreads();
#pragma unroll
    for (int it = 0; it < 4; ++it) {
        int idx = it * 64 + l;           // 0..255
        int r = idx >> 4;                // 0..15
        int ch = (idx & 15) * 8;         // 0..120
        int grow = bm + r;
        if (grow < N_NODES)
            *(short8v*)&xl[(size_t)grow * D + ch] = *(const short8v*)&lds[w][r][ch];
    }
}

// ---------------- aggregation: one wave per node, bf16x2 per lane ----------------
__global__ __launch_bounds__(256) void aggregate(const int* __restrict__ edges,
                                                 const int* __restrict__ rowptr,
                                                 const float* __restrict__ dinv,
                                                 const unsigned int* __restrict__ xl2,
                                                 float* __restrict__ out) {
    int gw = (blockIdx.x * 256 + threadIdx.x) >> 6;
    int lane = threadIdx.x & 63;
    if (gw >= N_NODES) return;
    int s = rowptr[gw];
    int e = rowptr[gw + 1];
    float dr = dinv[gw];
    float ax = 0.0f, ay = 0.0f;
    int i = s;
    for (; i + 4 <= e; i += 4) {
        int c0 = edges[i], c1 = edges[i + 1], c2 = edges[i + 2], c3 = edges[i + 3];
        float w0 = dr * dinv[c0], w1 = dr * dinv[c1];
        float w2 = dr * dinv[c2], w3 = dr * dinv[c3];
        unsigned int v0 = xl2[c0 * 64 + lane];
        unsigned int v1 = xl2[c1 * 64 + lane];
        unsigned int v2 = xl2[c2 * 64 + lane];
        unsigned int v3 = xl2[c3 * 64 + lane];
        ax += w0 * __uint_as_float(v0 << 16);
        ay += w0 * __uint_as_float(v0 & 0xffff0000u);
        ax += w1 * __uint_as_float(v1 << 16);
        ay += w1 * __uint_as_float(v1 & 0xffff0000u);
        ax += w2 * __uint_as_float(v2 << 16);
        ay += w2 * __uint_as_float(v2 & 0xffff0000u);
        ax += w3 * __uint_as_float(v3 << 16);
        ay += w3 * __uint_as_float(v3 & 0xffff0000u);
    }
    for (; i < e; ++i) {
        int c0 = edges[i];
        float w0 = dr * dinv[c0];
        unsigned int v0 = xl2[c0 * 64 + lane];
        ax += w0 * __uint_as_float(v0 << 16);
        ay += w0 * __uint_as_float(v0 & 0xffff0000u);
    }
    float2 r;
    r.x = ax;
    r.y = ay;
    *(float2*)&out[(size_t)gw * D + lane * 2] = r;
}

extern "C" void kernel_launch(void* const* d_in, const int* in_sizes, int n_in,
                              void* d_out, int out_size, void* d_ws, size_t ws_size,
                              hipStream_t stream) {
    const float* x  = (const float*)d_in[0];
    const int*   ei = (const int*)d_in[1];
    const float* W  = (const float*)d_in[2];
    const float* b  = (const float*)d_in[3];
    float* out = (float*)d_out;

    // workspace layout (4-byte units)
    unsigned int* ws = (unsigned int*)d_ws;
    __hip_bfloat16* xl = (__hip_bfloat16*)ws;                 // 12.8M bf16 = 6.4M u32
    __hip_bfloat16* Wb = (__hip_bfloat16*)(ws + 6400000);     // 16384 bf16 = 8192 u32
    int*   degcnt = (int*)(ws + 6408192);                     // 100,096
    float* dinv   = (float*)(ws + 6508288);                   // 100,096
    int*   rowptr = (int*)(ws + 6608384);                     // 100,160 (needs 100,001)
    int*   cursor = (int*)(ws + 6708544);                     // 100,096
    int*   bsums  = (int*)(ws + 6808640);                     // 128
    int*   edges  = (int*)(ws + 6808768);                     // 3.2M ints
    // total ≈ 10.0M u32 ≈ 40 MB

    hipMemsetAsync(degcnt, 0, N_NODES * sizeof(int), stream);

    count_deg<<<(N_EDGES + 255) / 256, 256, 0, stream>>>(ei, degcnt);

    const int nb = (N_NODES + 1023) / 1024;          // 98
    scan1<<<nb, 1024, 0, stream>>>(degcnt, rowptr, bsums);
    dinv_k<<<(N_NODES + 255) / 256, 256, 0, stream>>>(degcnt, dinv);
    convW<<<(D * D + 255) / 256, 256, 0, stream>>>(W, Wb);
    scan2<<<1, 128, 0, stream>>>(bsums, nb);
    scan3<<<(N_NODES + 255) / 256, 256, 0, stream>>>(rowptr, bsums, cursor);

    scatter_k<<<(N_EDGES + 255) / 256, 256, 0, stream>>>(ei, cursor, edges);

    gemm_mfma<<<(N_NODES + 63) / 64, 256, 0, stream>>>(x, Wb, b, xl);

    aggregate<<<(N_NODES * 64 + 255) / 256, 256, 0, stream>>>(
        edges, rowptr, dinv, (const unsigned int*)xl, out);
}

// Round 4
// 352.278 us; speedup vs baseline: 1.9209x; 1.9142x over previous
//
#include <hip/hip_runtime.h>
#include <hip/hip_bf16.h>

#define N_NODES 100000
#define N_EDGES 3200000
#define D 128
#define NB 782          // buckets: bin = row >> 7 (128 rows per bucket)
#define CAP 5120        // bucket capacity (mean 4092, sigma ~64 -> +16 sigma)
#define EPB 16          // edges per thread in partition_k (256 thr -> 4096/block)

typedef __attribute__((ext_vector_type(8))) short short8v;   // 8 bf16 (4 VGPRs)
typedef __attribute__((ext_vector_type(4))) float f32x4;

static __device__ __forceinline__ short f2bf(float f) {
    __hip_bfloat16 h = __float2bfloat16(f);
    return __builtin_bit_cast(short, h);
}

// ---------------- init bucket cursors ----------------
__global__ __launch_bounds__(256) void init_cursor(int* __restrict__ cursor) {
    int i = blockIdx.x * 256 + threadIdx.x;
    if (i < NB) cursor[i] = i * CAP;
}

// ---------------- pass 1: partition edges into row-buckets ----------------
// Per block: 4096 edges. LDS rank per bucket, ONE global atomicAdd per
// (block,bucket) to reserve a run, then write packed records to the run.
__global__ __launch_bounds__(256) void partition_k(const int* __restrict__ ei,
                                                   int* __restrict__ cursor,
                                                   int* __restrict__ staging) {
    __shared__ int lbin[NB];    // counts then global-run bases
    __shared__ int lcnt[NB];
    int tid = threadIdx.x;
    long long base = (long long)blockIdx.x * (256 * EPB);

    for (int i = tid; i < NB; i += 256) lbin[i] = 0;
    __syncthreads();

    int lrank[EPB];
#pragma unroll
    for (int j = 0; j < EPB; ++j) {
        long long e = base + j * 256 + tid;
        lrank[j] = -1;
        if (e < N_EDGES) {
            int r = ei[e];
            lrank[j] = atomicAdd(&lbin[r >> 7], 1);
        }
    }
    __syncthreads();
    // reserve runs
    for (int i = tid; i < NB; i += 256) {
        int c = lbin[i];
        lcnt[i] = c;
        if (c > 0) lbin[i] = atomicAdd(&cursor[i], c);
    }
    __syncthreads();
#pragma unroll
    for (int j = 0; j < EPB; ++j) {
        long long e = base + j * 256 + tid;
        if (e < N_EDGES) {
            int r = ei[e];
            int c = ei[N_EDGES + e];
            int bin = r >> 7;
            staging[lbin[bin] + lrank[j]] = (c << 7) | (r & 127);
        }
    }
    (void)lcnt;
}

// ---------------- scan bucket counts -> final CSR bases ----------------
__global__ __launch_bounds__(1024) void bscan_k(const int* __restrict__ cursor,
                                                int* __restrict__ fbase) {
    __shared__ int s[1024];
    int tid = threadIdx.x;
    int v = (tid < NB) ? (cursor[tid] - tid * CAP) : 0;
    s[tid] = v;
    __syncthreads();
    for (int off = 1; off < 1024; off <<= 1) {
        int t = (tid >= off) ? s[tid - off] : 0;
        __syncthreads();
        s[tid] += t;
        __syncthreads();
    }
    if (tid < NB) fbase[tid] = s[tid] - v;       // exclusive
    if (tid == NB - 1) fbase[NB] = s[tid];       // total (= N_EDGES)
}

// ---------------- pass 2: per-bucket exact CSR + rowptr + dinv ----------------
__global__ __launch_bounds__(256) void pass2_k(const int* __restrict__ staging,
                                               const int* __restrict__ cursor,
                                               const int* __restrict__ fbase,
                                               int* __restrict__ rowptr,
                                               float* __restrict__ dinv,
                                               int* __restrict__ edgesF) {
    __shared__ int hist[128];
    __shared__ int ssc[128];
    __shared__ int lrk[128];
    int bin = blockIdx.x;
    int tid = threadIdx.x;
    int cnt = cursor[bin] - bin * CAP;
    int fb = fbase[bin];
    int row0 = bin << 7;
    const int* st = staging + bin * CAP;

    if (tid < 128) { hist[tid] = 0; lrk[tid] = 0; }
    __syncthreads();
    for (int i = tid; i < cnt; i += 256)
        atomicAdd(&hist[st[i] & 127], 1);
    __syncthreads();
    if (tid < 128) ssc[tid] = hist[tid];
    __syncthreads();
    for (int off = 1; off < 128; off <<= 1) {
        int t = (tid < 128 && tid >= off) ? ssc[tid - off] : 0;
        __syncthreads();
        if (tid < 128) ssc[tid] += t;
        __syncthreads();
    }
    // ssc = inclusive scan; exclusive base = ssc[r] - hist[r]
    if (tid < 128) {
        int row = row0 + tid;
        if (row < N_NODES) {
            int deg = hist[tid];
            rowptr[row] = fb + ssc[tid] - deg;
            dinv[row] = (deg > 0) ? rsqrtf((float)deg) : 0.0f;
        }
    }
    if (bin == 0 && tid == 0) rowptr[N_NODES] = N_EDGES;
    __syncthreads();
    for (int i = tid; i < cnt; i += 256) {
        int rec = st[i];
        int r = rec & 127;
        int c = ((unsigned)rec) >> 7;
        int k = atomicAdd(&lrk[r], 1);
        edgesF[fb + ssc[r] - hist[r] + k] = c;
    }
}

// ---------------- W f32 -> bf16 ----------------
__global__ __launch_bounds__(256) void convW(const float* __restrict__ W,
                                             __hip_bfloat16* __restrict__ Wb) {
    int i = blockIdx.x * 256 + threadIdx.x;
    if (i < D * D) Wb[i] = __float2bfloat16(W[i]);
}

// ---------------- xl = bf16(x @ W.T + b), MFMA 16x16x32 ----------------
__global__ __launch_bounds__(256) void gemm_mfma(const float* __restrict__ x,
                                                 const __hip_bfloat16* __restrict__ Wb,
                                                 const float* __restrict__ b,
                                                 __hip_bfloat16* __restrict__ xl) {
    __shared__ __hip_bfloat16 lds[4][16][136];   // per-wave transpose buffer
    int tid = threadIdx.x;
    int w = tid >> 6;
    int l = tid & 63;
    int lm = l & 15;         // A-row / B-col within frag
    int kb = l >> 4;         // k-block 0..3
    int bm = blockIdx.x * 64 + w * 16;

    int row = bm + lm;
    if (row >= N_NODES) row = N_NODES - 1;       // dup compute; stores guarded
    const float* xr = x + (size_t)row * D;

    short8v a[4];
#pragma unroll
    for (int ks = 0; ks < 4; ++ks) {
        const float* p = xr + ks * 32 + kb * 8;
        float4 u = *(const float4*)p;
        float4 v = *(const float4*)(p + 4);
        short8v t;
        t[0] = f2bf(u.x); t[1] = f2bf(u.y); t[2] = f2bf(u.z); t[3] = f2bf(u.w);
        t[4] = f2bf(v.x); t[5] = f2bf(v.y); t[6] = f2bf(v.z); t[7] = f2bf(v.w);
        a[ks] = t;
    }

    f32x4 acc[8];
#pragma unroll
    for (int nf = 0; nf < 8; ++nf) {
        acc[nf][0] = 0.f; acc[nf][1] = 0.f; acc[nf][2] = 0.f; acc[nf][3] = 0.f;
    }

    const short8v* Wv = reinterpret_cast<const short8v*>(Wb);
#pragma unroll
    for (int ks = 0; ks < 4; ++ks) {
#pragma unroll
        for (int nf = 0; nf < 8; ++nf) {
            short8v bf = Wv[(nf * 16 + lm) * 16 + ks * 4 + kb];
            acc[nf] = __builtin_amdgcn_mfma_f32_16x16x32_bf16(a[ks], bf, acc[nf], 0, 0, 0);
        }
    }

#pragma unroll
    for (int nf = 0; nf < 8; ++nf) {
        float bias = b[nf * 16 + lm];
#pragma unroll
        for (int j = 0; j < 4; ++j) {
            lds[w][kb * 4 + j][nf * 16 + lm] = __float2bfloat16(acc[nf][j] + bias);
        }
    }
    __syncthreads();
#pragma unroll
    for (int it = 0; it < 4; ++it) {
        int idx = it * 64 + l;
        int r = idx >> 4;
        int ch = (idx & 15) * 8;
        int grow = bm + r;
        if (grow < N_NODES)
            *(short8v*)&xl[(size_t)grow * D + ch] = *(const short8v*)&lds[w][r][ch];
    }
}

// ---------------- aggregation: one wave per node, bf16x2 per lane ----------------
__global__ __launch_bounds__(256) void aggregate(const int* __restrict__ edges,
                                                 const int* __restrict__ rowptr,
                                                 const float* __restrict__ dinv,
                                                 const unsigned int* __restrict__ xl2,
                                                 float* __restrict__ out) {
    int gw = (blockIdx.x * 256 + threadIdx.x) >> 6;
    int lane = threadIdx.x & 63;
    if (gw >= N_NODES) return;
    int s = rowptr[gw];
    int e = rowptr[gw + 1];
    float dr = dinv[gw];
    float ax = 0.0f, ay = 0.0f;
    int i = s;
    for (; i + 4 <= e; i += 4) {
        int c0 = edges[i], c1 = edges[i + 1], c2 = edges[i + 2], c3 = edges[i + 3];
        float w0 = dr * dinv[c0], w1 = dr * dinv[c1];
        float w2 = dr * dinv[c2], w3 = dr * dinv[c3];
        unsigned int v0 = xl2[c0 * 64 + lane];
        unsigned int v1 = xl2[c1 * 64 + lane];
        unsigned int v2 = xl2[c2 * 64 + lane];
        unsigned int v3 = xl2[c3 * 64 + lane];
        ax += w0 * __uint_as_float(v0 << 16);
        ay += w0 * __uint_as_float(v0 & 0xffff0000u);
        ax += w1 * __uint_as_float(v1 << 16);
        ay += w1 * __uint_as_float(v1 & 0xffff0000u);
        ax += w2 * __uint_as_float(v2 << 16);
        ay += w2 * __uint_as_float(v2 & 0xffff0000u);
        ax += w3 * __uint_as_float(v3 << 16);
        ay += w3 * __uint_as_float(v3 & 0xffff0000u);
    }
    for (; i < e; ++i) {
        int c0 = edges[i];
        float w0 = dr * dinv[c0];
        unsigned int v0 = xl2[c0 * 64 + lane];
        ax += w0 * __uint_as_float(v0 << 16);
        ay += w0 * __uint_as_float(v0 & 0xffff0000u);
    }
    float2 r;
    r.x = ax;
    r.y = ay;
    *(float2*)&out[(size_t)gw * D + lane * 2] = r;
}

extern "C" void kernel_launch(void* const* d_in, const int* in_sizes, int n_in,
                              void* d_out, int out_size, void* d_ws, size_t ws_size,
                              hipStream_t stream) {
    const float* x  = (const float*)d_in[0];
    const int*   ei = (const int*)d_in[1];
    const float* W  = (const float*)d_in[2];
    const float* b  = (const float*)d_in[3];
    float* out = (float*)d_out;

    // workspace layout (4-byte units)
    unsigned int* ws = (unsigned int*)d_ws;
    __hip_bfloat16* xl = (__hip_bfloat16*)ws;                 // 12.8M bf16 = 6.4M u32
    __hip_bfloat16* Wb = (__hip_bfloat16*)(ws + 6400000);     // 16384 bf16 = 8192 u32
    float* dinv    = (float*)(ws + 6408192);                  // 100,096
    int*   rowptr  = (int*)(ws + 6508288);                    // 100,160 (needs 100,001)
    int*   cursor  = (int*)(ws + 6608448);                    // 800 (NB=782)
    int*   fbase   = (int*)(ws + 6609248);                    // 800 (NB+1)
    int*   edgesF  = (int*)(ws + 6610048);                    // 3.2M ints
    int*   staging = (int*)(ws + 9810048);                    // NB*CAP = 4,003,840 ints
    // total ≈ 13.8M u32 ≈ 55.3 MB

    init_cursor<<<(NB + 255) / 256, 256, 0, stream>>>(cursor);

    const int pblocks = (N_EDGES + 256 * EPB - 1) / (256 * EPB);   // 782
    partition_k<<<pblocks, 256, 0, stream>>>(ei, cursor, staging);

    bscan_k<<<1, 1024, 0, stream>>>(cursor, fbase);

    convW<<<(D * D + 255) / 256, 256, 0, stream>>>(W, Wb);

    pass2_k<<<NB, 256, 0, stream>>>(staging, cursor, fbase, rowptr, dinv, edgesF);

    gemm_mfma<<<(N_NODES + 63) / 64, 256, 0, stream>>>(x, Wb, b, xl);

    aggregate<<<(N_NODES * 64 + 255) / 256, 256, 0, stream>>>(
        edgesF, rowptr, dinv, (const unsigned int*)xl, out);
}